// Round 7
// baseline (322.720 us; speedup 1.0000x reference)
//
#include <hip/hip_runtime.h>
#include <math.h>

#define NNODES 65536
#define KNBR 27
#define EPS_BN 1e-5f
#define LOG_P 4.6151205168412597f

typedef float f32x4 __attribute__((ext_vector_type(4)));
typedef short s16x8 __attribute__((ext_vector_type(8)));   // 8 bf16 in 4 VGPRs

__device__ __forceinline__ unsigned short f2bf(float f) {
    union { float f; unsigned int u; } v; v.f = f;
    unsigned int u = v.u;
    unsigned int r = (u + 0x7fffu + ((u >> 16) & 1u)) >> 16;   // RNE
    return (unsigned short)r;
}

__device__ __forceinline__ void gload16(const void* g, void* l) {
    __builtin_amdgcn_global_load_lds(
        (const __attribute__((address_space(1))) void*)g,
        (__attribute__((address_space(3))) void*)l, 16, 0, 0);
}

// ---------------- W preprocessing for spconv: [k][cin][dout] f32 -> [k][dout][chunk swizzled] bf16 ----------------
__global__ __launch_bounds__(256) void prep_w_kernel(
    const float* __restrict__ W, unsigned short* __restrict__ wpre, int CIN, int NCH)
{
    const int idx = blockIdx.x * 256 + threadIdx.x;
    const int total = KNBR * 96 * NCH * 8;
    if (idx >= total) return;
    const int e  = idx & 7;
    const int t1 = idx >> 3;
    const int ci = t1 % NCH;
    const int t2 = t1 / NCH;
    const int r  = t2 % 96;
    const int k  = t2 / 96;
    const int cc  = ci ^ (r & (NCH - 1));
    const int cin = cc * 8 + e;
    float v = (cin < CIN) ? W[((size_t)k * CIN + cin) * 96 + r] : 0.f;
    wpre[idx] = f2bf(v);
}

// ---------------- prep for fused phase-1 B image: [3 kt][384 col][4 pos][8 e] bf16 ----------------
__global__ __launch_bounds__(256) void prep_wc1h_kernel(
    const float* __restrict__ w_clip1, const float* __restrict__ w_lab,
    const float* __restrict__ w_unlab, const float* __restrict__ w_over,
    unsigned short* __restrict__ out)
{
    const int idx = blockIdx.x * 256 + threadIdx.x;
    if (idx >= 3 * 384 * 32) return;
    const int e   = idx & 7;
    const int p2  = (idx >> 3) & 3;
    const int col = (idx >> 5) % 384;
    const int kt  = (idx >> 5) / 384;
    const int cin = (kt * 4 + (p2 ^ ((col >> 2) & 3))) * 8 + e;
    float v;
    if (col < 256)      v = w_clip1[(size_t)cin * 256 + col];
    else if (col < 275) v = w_lab[(size_t)cin * 19 + (col - 256)];
    else if (col < 300) { int jj = col - 275, hh = jj / 5,  p = jj - hh * 5;  v = w_unlab[((size_t)hh * 96 + cin) * 5  + p]; }
    else if (col < 375) { int jj = col - 300, hh = jj / 15, p = jj - hh * 15; v = w_over [((size_t)hh * 96 + cin) * 15 + p]; }
    else v = 0.f;
    out[idx] = f2bf(v);
}

// ---------------- prep for fused phase-2 B image: [8 kt][512 col][4 pos][8 e] bf16 ----------------
__global__ __launch_bounds__(256) void prep_wc2_kernel(
    const float* __restrict__ w_clip2, unsigned short* __restrict__ out)
{
    const int idx = blockIdx.x * 256 + threadIdx.x;   // 131072 total
    const int e   = idx & 7;
    const int p2  = (idx >> 3) & 3;
    const int col = (idx >> 5) & 511;
    const int kt  = idx >> 14;
    const int cin = (kt * 4 + (p2 ^ ((col >> 2) & 3))) * 8 + e;
    out[idx] = f2bf(w_clip2[(size_t)cin * 512 + col]);
}

// ---------------- stage 1: entropy gate + rgb/img matvec -> x64 (bf16) ----------------
__global__ __launch_bounds__(256) void stage1_kernel(
    const float* __restrict__ feats,
    const float* __restrict__ w_rgb, const float* __restrict__ b_rgb, const float* __restrict__ bn_rgb,
    const float* __restrict__ w_img, const float* __restrict__ b_img, const float* __restrict__ bn_img,
    unsigned short* __restrict__ x64b)
{
    __shared__ float s_f[4][106];
    const int wid  = threadIdx.x >> 6;
    const int lane = threadIdx.x & 63;
    const int n = blockIdx.x * 4 + wid;
    const float* fr = feats + (size_t)n * 105;
    for (int i = lane; i < 105; i += 64) s_f[wid][i] = fr[i];
    __syncthreads();

    float s = 0.f;
    for (int i = lane; i < 101; i += 64) {
        float pv = s_f[wid][4 + i];
        float ps = fmaxf(pv, 1e-12f);
        s += ps * logf(ps);
    }
    #pragma unroll
    for (int off = 32; off > 0; off >>= 1) s += __shfl_xor(s, off, 64);
    const float wgt = 1.0f + s * (1.0f / LOG_P);

    if (lane < 32) {
        const int j = lane;
        float acc = b_rgb[j];
        #pragma unroll
        for (int c = 0; c < 4; ++c) acc += s_f[wid][c] * w_rgb[c*32 + j];
        float y = bn_rgb[j] * (acc - bn_rgb[64+j]) * rsqrtf(bn_rgb[96+j] + EPS_BN) + bn_rgb[32+j];
        x64b[(size_t)n*64 + j] = f2bf(fmaxf(y, 0.f));
    } else {
        const int j = lane - 32;
        float acc = 0.f;
        for (int c = 0; c < 101; ++c) acc += s_f[wid][4+c] * w_img[c*32 + j];
        acc = acc * wgt + b_img[j];
        float y = bn_img[j] * (acc - bn_img[64+j]) * rsqrtf(bn_img[96+j] + EPS_BN) + bn_img[32+j];
        x64b[(size_t)n*64 + 32 + j] = f2bf(fmaxf(y, 0.f));
    }
}

// ---------------- spconv via MFMA: r4 per-wave math, 512 thr (8 waves) share one W stage ----------------
// 256 nodes/block, grid 256, 2 blocks/CU -> 16 waves/CU (4/SIMD) for gather-latency hiding
template<int CIN, bool OUTBF>
__global__ __launch_bounds__(512, 4) void spconv_mfma(
    const char* __restrict__ xinb,
    const int*  __restrict__ nbr,
    const char* __restrict__ wpre,
    const float* __restrict__ bnp,
    float* __restrict__ outf,
    unsigned short* __restrict__ outb)
{
    constexpr int KT   = CIN / 32;
    constexpr int NCH  = (CIN == 96) ? 16 : 8;
    constexpr int CM   = NCH - 1;
    constexpr int ROWB = NCH * 16;
    constexpr int BUFB = 96 * ROWB;              // 24576 / 12288

    __shared__ int s_nbr[256 * KNBR];
    __shared__ __align__(16) char s_b[2][BUFB];

    const int t   = threadIdx.x;
    const int wid = t >> 6;
    const int l   = t & 63;
    const int l15 = l & 15;
    const int l4  = l >> 4;
    const int n0  = blockIdx.x * 256;

    for (int i = t; i < 256 * KNBR; i += 512) s_nbr[i] = nbr[(size_t)n0 * KNBR + i];

    f32x4 acc[2][6];
    #pragma unroll
    for (int mt = 0; mt < 2; ++mt)
        #pragma unroll
        for (int nt = 0; nt < 6; ++nt) acc[mt][nt] = (f32x4){0.f, 0.f, 0.f, 0.f};

    s16x8 a0[2][KT], a1[2][KT], a2r[2][KT];

#define STAGE(kk) do {                                                         \
    const char* _src = wpre + (size_t)(kk) * BUFB;                             \
    char* _dst = &s_b[(kk) & 1][0];                                            \
    if (CIN == 96) {                                                           \
        _Pragma("unroll")                                                      \
        for (int _i = 0; _i < 3; ++_i)                                         \
            gload16(_src + _i * 8192 + t * 16, _dst + _i * 8192 + (wid << 10));\
    } else {                                                                   \
        gload16(_src + t * 16, _dst + (wid << 10));                            \
        if (wid < 4)                                                           \
            gload16(_src + 8192 + t * 16, _dst + 8192 + (wid << 10));          \
    }                                                                          \
} while (0)

#define PRE(areg, kk) do {                                                     \
    _Pragma("unroll")                                                          \
    for (int _mt = 0; _mt < 2; ++_mt) {                                        \
        const int _nb = s_nbr[(wid * 32 + _mt * 16 + l15) * KNBR + (kk)];      \
        const char* _rp = xinb + (size_t)_nb * (CIN * 2) + (l4 << 4);          \
        _Pragma("unroll")                                                      \
        for (int _kt = 0; _kt < KT; ++_kt)                                     \
            areg[_mt][_kt] = *(const s16x8*)(_rp + _kt * 64);                  \
    }                                                                          \
} while (0)

#define COMP(areg, kk) do {                                                    \
    const char* _bb = &s_b[(kk) & 1][0];                                       \
    _Pragma("unroll")                                                          \
    for (int _kt = 0; _kt < KT; ++_kt) {                                       \
        s16x8 _bf[6];                                                          \
        _Pragma("unroll")                                                      \
        for (int _nt = 0; _nt < 6; ++_nt) {                                    \
            const int _row = _nt * 16 + l15;                                   \
            const int _c   = _kt * 4 + l4;                                     \
            _bf[_nt] = *(const s16x8*)(_bb + _row * ROWB + ((_c ^ (_row & CM)) << 4)); \
        }                                                                      \
        _Pragma("unroll")                                                      \
        for (int _nt = 0; _nt < 6; ++_nt) {                                    \
            acc[0][_nt] = __builtin_amdgcn_mfma_f32_16x16x32_bf16(areg[0][_kt], _bf[_nt], acc[0][_nt], 0, 0, 0); \
            acc[1][_nt] = __builtin_amdgcn_mfma_f32_16x16x32_bf16(areg[1][_kt], _bf[_nt], acc[1][_nt], 0, 0, 0); \
        }                                                                      \
    }                                                                          \
} while (0)

    __syncthreads();                 // s_nbr ready
    PRE(a0, 0);
    PRE(a1, 1);
    STAGE(0);
    __syncthreads();

    for (int k = 0; k < 27; k += 3) {
        STAGE(k + 1);
        PRE(a2r, k + 2);
        COMP(a0, k);
        __syncthreads();
        STAGE(k + 2);
        if (k + 3 < 27) PRE(a0, k + 3);
        COMP(a1, k + 1);
        __syncthreads();
        if (k + 3 < 27) STAGE(k + 3);
        if (k + 4 < 27) PRE(a1, k + 4);
        COMP(a2r, k + 2);
        __syncthreads();
    }

#undef STAGE
#undef PRE
#undef COMP

    // epilogue: bn + relu; C/D layout col=lane&15, row=(lane>>4)*4+q
    #pragma unroll
    for (int mt = 0; mt < 2; ++mt)
        #pragma unroll
        for (int nt = 0; nt < 6; ++nt) {
            const int d = nt * 16 + l15;
            const float sc = bnp[d] * rsqrtf(bnp[288 + d] + EPS_BN);
            const float mb = bnp[192 + d];
            const float bb = bnp[96 + d];
            #pragma unroll
            for (int q = 0; q < 4; ++q) {
                const int node = n0 + wid * 32 + mt * 16 + l4 * 4 + q;
                float y = sc * (acc[mt][nt][q] - mb) + bb;
                y = fmaxf(y, 0.f);
                if (OUTBF) outb[(size_t)node * 96 + d] = f2bf(y);
                else       outf[(size_t)node * 96 + d] = y;
            }
        }
}

// ---------------- fused clip1 + heads + clip2 (unchanged from round 4) ----------------
__global__ __launch_bounds__(512, 2) void fused_clip_heads(
    const float* __restrict__ x,
    const char* __restrict__ wc1h,          // [3][384][4][8] bf16 image
    const char* __restrict__ wc2,           // [8][512][4][8] bf16 image
    const float* __restrict__ b_clip1, const float* __restrict__ bn_clip,
    const float* __restrict__ b_clip2,
    float* __restrict__ out_lab, float* __restrict__ out_unlab, float* __restrict__ out_over,
    float* __restrict__ outc)
{
    extern __shared__ __align__(16) char lds[];
    char* reg0 = lds;            // 65536
    char* s_h  = lds + 65536;    // 65536

    const int t   = threadIdx.x;
    const int wid = t >> 6;
    const int l   = t & 63;
    const int l15 = l & 15;
    const int l4  = l >> 4;
    const int wm  = wid >> 2;
    const int wn  = wid & 3;
    const int r0  = blockIdx.x * 128;

#define STG1(kt) do {                                                          \
    const char* _s = wc1h + (size_t)(kt) * 24576;                              \
    char* _d = reg0 + ((kt) & 1) * 32768;                                      \
    _Pragma("unroll")                                                          \
    for (int _i = 0; _i < 3; ++_i)                                             \
        gload16(_s + _i * 8192 + t * 16, _d + _i * 8192 + (wid << 10));        \
} while (0)

#define STG2(kt) do {                                                          \
    const char* _s = wc2 + (size_t)(kt) * 32768;                               \
    char* _d = reg0 + ((kt) & 1) * 32768;                                      \
    _Pragma("unroll")                                                          \
    for (int _i = 0; _i < 4; ++_i)                                             \
        gload16(_s + _i * 8192 + t * 16, _d + _i * 8192 + (wid << 10));        \
} while (0)

    // ================= phase 1 =================
    STG1(0);

    s16x8 af[3][4];
    #pragma unroll
    for (int kt = 0; kt < 3; ++kt)
        #pragma unroll
        for (int mt = 0; mt < 4; ++mt) {
            const int r = r0 + wm*64 + mt*16 + l15;
            const float* bp = x + (size_t)r*96 + kt*32 + l4*8;
            const float4 xa = *(const float4*)bp;
            const float4 xb = *(const float4*)(bp + 4);
            s16x8 v;
            v[0]=(short)f2bf(xa.x); v[1]=(short)f2bf(xa.y); v[2]=(short)f2bf(xa.z); v[3]=(short)f2bf(xa.w);
            v[4]=(short)f2bf(xb.x); v[5]=(short)f2bf(xb.y); v[6]=(short)f2bf(xb.z); v[7]=(short)f2bf(xb.w);
            af[kt][mt] = v;
        }

    f32x4 acc1[4][6];
    #pragma unroll
    for (int mt = 0; mt < 4; ++mt)
        #pragma unroll
        for (int nt = 0; nt < 6; ++nt) acc1[mt][nt] = (f32x4){0.f,0.f,0.f,0.f};

    __syncthreads();

    for (int kt = 0; kt < 3; ++kt) {
        if (kt < 2) STG1(kt + 1);
        const char* buf = reg0 + (kt & 1) * 32768;
        s16x8 bf[6];
        #pragma unroll
        for (int nt = 0; nt < 6; ++nt) {
            const int col = wn*96 + nt*16 + l15;
            bf[nt] = *(const s16x8*)(buf + col*64 + ((l4 ^ ((col >> 2) & 3)) << 4));
        }
        #pragma unroll
        for (int nt = 0; nt < 6; ++nt)
            #pragma unroll
            for (int mt = 0; mt < 4; ++mt)
                acc1[mt][nt] = __builtin_amdgcn_mfma_f32_16x16x32_bf16(af[kt][mt], bf[nt], acc1[mt][nt], 0, 0, 0);
        __syncthreads();
    }

    STG2(0);

    #pragma unroll
    for (int nt = 0; nt < 6; ++nt) {
        const int j = wn*96 + nt*16 + l15;
        if (j < 256) {
            const float sc = bn_clip[j] * rsqrtf(bn_clip[768 + j] + EPS_BN);
            const float mb = bn_clip[512 + j];
            const float bb = bn_clip[256 + j];
            const float bias = b_clip1[j];
            const int c = j >> 3, e = j & 7;
            #pragma unroll
            for (int mt = 0; mt < 4; ++mt)
                #pragma unroll
                for (int q = 0; q < 4; ++q) {
                    const int row = wm*64 + mt*16 + l4*4 + q;
                    float y = fmaxf(sc * (acc1[mt][nt][q] + bias - mb) + bb, 0.f);
                    *(unsigned short*)(s_h + row*512 + ((c ^ (row & 31)) << 4) + e*2) = f2bf(y);
                }
        } else if (j < 375) {
            const int jh = j - 256;
            #pragma unroll
            for (int mt = 0; mt < 4; ++mt)
                #pragma unroll
                for (int q = 0; q < 4; ++q) {
                    const int n = r0 + wm*64 + mt*16 + l4*4 + q;
                    const float v = acc1[mt][nt][q];
                    if (jh < 19)      out_lab[(size_t)n*19 + jh] = v;
                    else if (jh < 44) { int jj = jh-19, hh = jj/5,  p = jj-hh*5;  out_unlab[((size_t)hh*NNODES + n)*5  + p] = v; }
                    else              { int jj = jh-44, hh = jj/15, p = jj-hh*15; out_over [((size_t)hh*NNODES + n)*15 + p] = v; }
                }
        }
    }
    __syncthreads();

    // ================= phase 2: h @ w_clip2 =================
    f32x4 acc2[4][8];
    #pragma unroll
    for (int mt = 0; mt < 4; ++mt)
        #pragma unroll
        for (int nt = 0; nt < 8; ++nt) acc2[mt][nt] = (f32x4){0.f,0.f,0.f,0.f};

    for (int kt = 0; kt < 8; ++kt) {
        if (kt < 7) STG2(kt + 1);
        const char* buf = reg0 + (kt & 1) * 32768;
        s16x8 a2[4];
        #pragma unroll
        for (int mt = 0; mt < 4; ++mt) {
            const int row = wm*64 + mt*16 + l15;
            a2[mt] = *(const s16x8*)(s_h + row*512 + (((kt*4 + l4) ^ (row & 31)) << 4));
        }
        s16x8 b2[8];
        #pragma unroll
        for (int nt = 0; nt < 8; ++nt) {
            const int col = wn*128 + nt*16 + l15;
            b2[nt] = *(const s16x8*)(buf + col*64 + ((l4 ^ ((col >> 2) & 3)) << 4));
        }
        #pragma unroll
        for (int nt = 0; nt < 8; ++nt)
            #pragma unroll
            for (int mt = 0; mt < 4; ++mt)
                acc2[mt][nt] = __builtin_amdgcn_mfma_f32_16x16x32_bf16(a2[mt], b2[nt], acc2[mt][nt], 0, 0, 0);
        __syncthreads();
    }
#undef STG1
#undef STG2

    #pragma unroll
    for (int nt = 0; nt < 8; ++nt) {
        const int col = wn*128 + nt*16 + l15;
        const float bb = b_clip2[col];
        #pragma unroll
        for (int mt = 0; mt < 4; ++mt)
            #pragma unroll
            for (int q = 0; q < 4; ++q) {
                const int row = wm*64 + mt*16 + l4*4 + q;
                outc[(size_t)(r0 + row)*512 + col] = acc2[mt][nt][q] + bb;
            }
    }
}

extern "C" void kernel_launch(void* const* d_in, const int* in_sizes, int n_in,
                              void* d_out, int out_size, void* d_ws, size_t ws_size,
                              hipStream_t stream)
{
    const float* feats   = (const float*)d_in[0];
    const int*   nbr1    = (const int*)  d_in[1];
    const int*   nbr2    = (const int*)  d_in[2];
    const float* w_rgb   = (const float*)d_in[3];
    const float* b_rgb   = (const float*)d_in[4];
    const float* bn_rgb  = (const float*)d_in[5];
    const float* w_img   = (const float*)d_in[6];
    const float* b_img   = (const float*)d_in[7];
    const float* bn_img  = (const float*)d_in[8];
    const float* w_e1    = (const float*)d_in[9];
    const float* w_e2    = (const float*)d_in[10];
    const float* bn_e1   = (const float*)d_in[11];
    const float* bn_e2   = (const float*)d_in[12];
    const float* w_lab   = (const float*)d_in[13];
    const float* w_unlab = (const float*)d_in[14];
    const float* w_over  = (const float*)d_in[15];
    const float* w_clip1 = (const float*)d_in[16];
    const float* b_clip1 = (const float*)d_in[17];
    const float* bn_clip = (const float*)d_in[18];
    const float* w_clip2 = (const float*)d_in[19];
    const float* b_clip2 = (const float*)d_in[20];

    float* out = (float*)d_out;
    const size_t off_unlab = (size_t)NNODES * 19;
    const size_t off_over  = (size_t)NNODES * 44;
    const size_t off_x     = (size_t)NNODES * 119;
    const size_t off_clip  = (size_t)NNODES * 215;

    // intermediates inside clip-feats output region — only read by kernels that
    // run BEFORE fused_clip_heads (the sole writer of this region)
    char* scratch = (char*)(out + off_clip);
    unsigned short* x64b  = (unsigned short*)scratch;                   // 8 MB
    unsigned short* x96b  = (unsigned short*)(scratch + (8u << 20));    // 12.6 MB
    unsigned short* wpre1 = (unsigned short*)(scratch + (21u << 20));   // 332 KB
    unsigned short* wpre2 = (unsigned short*)(scratch + (22u << 20));   // 664 KB

    // weight images read BY fused_clip_heads live in d_ws (336 KB)
    char* wc1h = (char*)d_ws;               // 73728 B
    char* wc2  = (char*)d_ws + 73728;       // 262144 B

    prep_w_kernel<<<(KNBR*96*8*8  + 255) / 256, 256, 0, stream>>>(w_e1, wpre1, 64, 8);
    prep_w_kernel<<<(KNBR*96*16*8 + 255) / 256, 256, 0, stream>>>(w_e2, wpre2, 96, 16);
    prep_wc1h_kernel<<<(3*384*32 + 255) / 256, 256, 0, stream>>>(w_clip1, w_lab, w_unlab, w_over,
                                                                 (unsigned short*)wc1h);
    prep_wc2_kernel<<<131072 / 256, 256, 0, stream>>>(w_clip2, (unsigned short*)wc2);

    stage1_kernel<<<NNODES/4, 256, 0, stream>>>(feats, w_rgb, b_rgb, bn_rgb, w_img, b_img, bn_img, x64b);

    spconv_mfma<64, true ><<<NNODES/256, 512, 0, stream>>>((const char*)x64b, nbr1, (const char*)wpre1,
                                                           bn_e1, nullptr, x96b);
    spconv_mfma<96, false><<<NNODES/256, 512, 0, stream>>>((const char*)x96b, nbr2, (const char*)wpre2,
                                                           bn_e2, out + off_x, nullptr);

    fused_clip_heads<<<NNODES/128, 512, 131072, stream>>>(
        out + off_x, wc1h, wc2, b_clip1, bn_clip, b_clip2,
        out, out + off_unlab, out + off_over, out + off_clip);
}

// Round 8
// 241.450 us; speedup vs baseline: 1.3366x; 1.3366x over previous
//
#include <hip/hip_runtime.h>
#include <math.h>

#define NNODES 65536
#define KNBR 27
#define EPS_BN 1e-5f
#define LOG_P 4.6151205168412597f

typedef float f32x4 __attribute__((ext_vector_type(4)));
typedef short s16x8 __attribute__((ext_vector_type(8)));   // 8 bf16 in 4 VGPRs

__device__ __forceinline__ unsigned short f2bf(float f) {
    union { float f; unsigned int u; } v; v.f = f;
    unsigned int u = v.u;
    unsigned int r = (u + 0x7fffu + ((u >> 16) & 1u)) >> 16;   // RNE
    return (unsigned short)r;
}

__device__ __forceinline__ void gload16(const void* g, void* l) {
    __builtin_amdgcn_global_load_lds(
        (const __attribute__((address_space(1))) void*)g,
        (__attribute__((address_space(3))) void*)l, 16, 0, 0);
}

// ---------------- W preprocessing for spconv: [k][cin][dout] f32 -> [k][dout][chunk swizzled] bf16 ----------------
__global__ __launch_bounds__(256) void prep_w_kernel(
    const float* __restrict__ W, unsigned short* __restrict__ wpre, int CIN, int NCH)
{
    const int idx = blockIdx.x * 256 + threadIdx.x;
    const int total = KNBR * 96 * NCH * 8;
    if (idx >= total) return;
    const int e  = idx & 7;
    const int t1 = idx >> 3;
    const int ci = t1 % NCH;
    const int t2 = t1 / NCH;
    const int r  = t2 % 96;
    const int k  = t2 / 96;
    const int cc  = ci ^ (r & (NCH - 1));
    const int cin = cc * 8 + e;
    float v = (cin < CIN) ? W[((size_t)k * CIN + cin) * 96 + r] : 0.f;
    wpre[idx] = f2bf(v);
}

// ---------------- prep for fused phase-1 B image: [3 kt][384 col][4 pos][8 e] bf16 ----------------
__global__ __launch_bounds__(256) void prep_wc1h_kernel(
    const float* __restrict__ w_clip1, const float* __restrict__ w_lab,
    const float* __restrict__ w_unlab, const float* __restrict__ w_over,
    unsigned short* __restrict__ out)
{
    const int idx = blockIdx.x * 256 + threadIdx.x;
    if (idx >= 3 * 384 * 32) return;
    const int e   = idx & 7;
    const int p2  = (idx >> 3) & 3;
    const int col = (idx >> 5) % 384;
    const int kt  = (idx >> 5) / 384;
    const int cin = (kt * 4 + (p2 ^ ((col >> 2) & 3))) * 8 + e;
    float v;
    if (col < 256)      v = w_clip1[(size_t)cin * 256 + col];
    else if (col < 275) v = w_lab[(size_t)cin * 19 + (col - 256)];
    else if (col < 300) { int jj = col - 275, hh = jj / 5,  p = jj - hh * 5;  v = w_unlab[((size_t)hh * 96 + cin) * 5  + p]; }
    else if (col < 375) { int jj = col - 300, hh = jj / 15, p = jj - hh * 15; v = w_over [((size_t)hh * 96 + cin) * 15 + p]; }
    else v = 0.f;
    out[idx] = f2bf(v);
}

// ---------------- prep for fused phase-2 B image: [8 kt][512 col][4 pos][8 e] bf16 ----------------
__global__ __launch_bounds__(256) void prep_wc2_kernel(
    const float* __restrict__ w_clip2, unsigned short* __restrict__ out)
{
    const int idx = blockIdx.x * 256 + threadIdx.x;   // 131072 total
    const int e   = idx & 7;
    const int p2  = (idx >> 3) & 3;
    const int col = (idx >> 5) & 511;
    const int kt  = idx >> 14;
    const int cin = (kt * 4 + (p2 ^ ((col >> 2) & 3))) * 8 + e;
    out[idx] = f2bf(w_clip2[(size_t)cin * 512 + col]);
}

// ---------------- stage 1: entropy gate + rgb/img matvec -> x64 (bf16) ----------------
__global__ __launch_bounds__(256) void stage1_kernel(
    const float* __restrict__ feats,
    const float* __restrict__ w_rgb, const float* __restrict__ b_rgb, const float* __restrict__ bn_rgb,
    const float* __restrict__ w_img, const float* __restrict__ b_img, const float* __restrict__ bn_img,
    unsigned short* __restrict__ x64b)
{
    __shared__ float s_f[4][106];
    const int wid  = threadIdx.x >> 6;
    const int lane = threadIdx.x & 63;
    const int n = blockIdx.x * 4 + wid;
    const float* fr = feats + (size_t)n * 105;
    for (int i = lane; i < 105; i += 64) s_f[wid][i] = fr[i];
    __syncthreads();

    float s = 0.f;
    for (int i = lane; i < 101; i += 64) {
        float pv = s_f[wid][4 + i];
        float ps = fmaxf(pv, 1e-12f);
        s += ps * logf(ps);
    }
    #pragma unroll
    for (int off = 32; off > 0; off >>= 1) s += __shfl_xor(s, off, 64);
    const float wgt = 1.0f + s * (1.0f / LOG_P);

    if (lane < 32) {
        const int j = lane;
        float acc = b_rgb[j];
        #pragma unroll
        for (int c = 0; c < 4; ++c) acc += s_f[wid][c] * w_rgb[c*32 + j];
        float y = bn_rgb[j] * (acc - bn_rgb[64+j]) * rsqrtf(bn_rgb[96+j] + EPS_BN) + bn_rgb[32+j];
        x64b[(size_t)n*64 + j] = f2bf(fmaxf(y, 0.f));
    } else {
        const int j = lane - 32;
        float acc = 0.f;
        for (int c = 0; c < 101; ++c) acc += s_f[wid][4+c] * w_img[c*32 + j];
        acc = acc * wgt + b_img[j];
        float y = bn_img[j] * (acc - bn_img[64+j]) * rsqrtf(bn_img[96+j] + EPS_BN) + bn_img[32+j];
        x64b[(size_t)n*64 + 32 + j] = f2bf(fmaxf(y, 0.f));
    }
}

// ---------------- spconv via MFMA: r4 geometry + T4 counted-vmcnt barriers ----------------
// 256 thr (4 waves), 128 nodes/block, grid 512; wave = 2 mtiles(16 nodes) x 6 ntiles(16 dout).
// k-loop barriers wait vmcnt(nPRE) (not 0): W-stage gload_lds forced complete, A-gather
// register loads (issued 2 phases ahead) stay in flight across barriers.
template<int CIN, bool OUTBF>
__global__ __launch_bounds__(256, 2) void spconv_mfma(
    const char* __restrict__ xinb,
    const int*  __restrict__ nbr,
    const char* __restrict__ wpre,
    const float* __restrict__ bnp,
    float* __restrict__ outf,
    unsigned short* __restrict__ outb)
{
    constexpr int KT   = CIN / 32;
    constexpr int NCH  = (CIN == 96) ? 16 : 8;
    constexpr int CM   = NCH - 1;
    constexpr int ROWB = NCH * 16;
    constexpr int STG  = (96 * ROWB) / 4096;

    __shared__ int s_nbr[128 * KNBR];
    __shared__ __align__(16) char s_b[2][96 * ROWB];

    const int t   = threadIdx.x;
    const int wid = t >> 6;
    const int l   = t & 63;
    const int l15 = l & 15;
    const int l4  = l >> 4;
    const int n0  = blockIdx.x * 128;

    for (int i = t; i < 128 * KNBR; i += 256) s_nbr[i] = nbr[(size_t)n0 * KNBR + i];

    f32x4 acc[2][6];
    #pragma unroll
    for (int mt = 0; mt < 2; ++mt)
        #pragma unroll
        for (int nt = 0; nt < 6; ++nt) acc[mt][nt] = (f32x4){0.f, 0.f, 0.f, 0.f};

    s16x8 a0[2][KT], a1[2][KT], a2r[2][KT];

// STAGE issues STG gload_lds (vmcnt FIFO: older than the PRE that follows).
// Trailing empty asm pins issue order so the vmcnt spare-window math holds.
#define STAGE(kk) do {                                                         \
    const char* _src = wpre + (size_t)(kk) * (96 * ROWB);                      \
    char* _dst = &s_b[(kk) & 1][0];                                            \
    _Pragma("unroll")                                                          \
    for (int _i = 0; _i < STG; ++_i)                                           \
        gload16(_src + _i * 4096 + t * 16, _dst + _i * 4096 + (wid << 10));    \
    asm volatile("" ::: "memory");                                             \
} while (0)

#define PRE(areg, kk) do {                                                     \
    _Pragma("unroll")                                                          \
    for (int _mt = 0; _mt < 2; ++_mt) {                                        \
        const int _nb = s_nbr[(wid * 32 + _mt * 16 + l15) * KNBR + (kk)];      \
        const char* _rp = xinb + (size_t)_nb * (CIN * 2) + (l4 << 4);          \
        _Pragma("unroll")                                                      \
        for (int _kt = 0; _kt < KT; ++_kt)                                     \
            areg[_mt][_kt] = *(const s16x8*)(_rp + _kt * 64);                  \
    }                                                                          \
} while (0)

#define COMP(areg, kk) do {                                                    \
    const char* _bb = &s_b[(kk) & 1][0];                                       \
    _Pragma("unroll")                                                          \
    for (int _kt = 0; _kt < KT; ++_kt) {                                       \
        s16x8 _bf[6];                                                          \
        _Pragma("unroll")                                                      \
        for (int _nt = 0; _nt < 6; ++_nt) {                                    \
            const int _row = _nt * 16 + l15;                                   \
            const int _c   = _kt * 4 + l4;                                     \
            _bf[_nt] = *(const s16x8*)(_bb + _row * ROWB + ((_c ^ (_row & CM)) << 4)); \
        }                                                                      \
        _Pragma("unroll")                                                      \
        for (int _nt = 0; _nt < 6; ++_nt) {                                    \
            acc[0][_nt] = __builtin_amdgcn_mfma_f32_16x16x32_bf16(areg[0][_kt], _bf[_nt], acc[0][_nt], 0, 0, 0); \
            acc[1][_nt] = __builtin_amdgcn_mfma_f32_16x16x32_bf16(areg[1][_kt], _bf[_nt], acc[1][_nt], 0, 0, 0); \
        }                                                                      \
    }                                                                          \
} while (0)

// counted-vmcnt barrier: spare the newest 2*KT loads (= this phase's PRE gathers),
// force everything older (this phase's STAGE) complete. memory clobber keeps
// post-barrier ds_reads below and pre-barrier ds_reads above.
#define KBAR() do {                                                            \
    if (KT == 3) asm volatile("s_waitcnt vmcnt(6)" ::: "memory");              \
    else         asm volatile("s_waitcnt vmcnt(4)" ::: "memory");              \
    __builtin_amdgcn_s_barrier();                                              \
} while (0)

    __syncthreads();                 // s_nbr ready
    PRE(a0, 0);
    PRE(a1, 1);
    STAGE(0);
    __syncthreads();                 // prologue full drain (once)

    for (int k = 0; k < 24; k += 3) {
        STAGE(k + 1);
        PRE(a2r, k + 2);
        COMP(a0, k);
        KBAR();
        STAGE(k + 2);
        PRE(a0, k + 3);
        COMP(a1, k + 1);
        KBAR();
        STAGE(k + 3);
        PRE(a1, k + 4);
        COMP(a2r, k + 2);
        KBAR();
    }
    // tail k = 24,25,26 (no further PRE; vmcnt(0) where spare-window would be empty)
    STAGE(25);
    PRE(a2r, 26);
    COMP(a0, 24);
    KBAR();
    STAGE(26);
    COMP(a1, 25);
    asm volatile("s_waitcnt vmcnt(0)" ::: "memory");
    __builtin_amdgcn_s_barrier();
    COMP(a2r, 26);

#undef STAGE
#undef PRE
#undef COMP
#undef KBAR

    // epilogue: bn + relu; C/D layout col=lane&15, row=(lane>>4)*4+q
    #pragma unroll
    for (int mt = 0; mt < 2; ++mt)
        #pragma unroll
        for (int nt = 0; nt < 6; ++nt) {
            const int d = nt * 16 + l15;
            const float sc = bnp[d] * rsqrtf(bnp[288 + d] + EPS_BN);
            const float mb = bnp[192 + d];
            const float bb = bnp[96 + d];
            #pragma unroll
            for (int q = 0; q < 4; ++q) {
                const int node = n0 + wid * 32 + mt * 16 + l4 * 4 + q;
                float y = sc * (acc[mt][nt][q] - mb) + bb;
                y = fmaxf(y, 0.f);
                if (OUTBF) outb[(size_t)node * 96 + d] = f2bf(y);
                else       outf[(size_t)node * 96 + d] = y;
            }
        }
}

// ---------------- fused clip1 + heads + clip2 (unchanged from round 4) ----------------
__global__ __launch_bounds__(512, 2) void fused_clip_heads(
    const float* __restrict__ x,
    const char* __restrict__ wc1h,          // [3][384][4][8] bf16 image
    const char* __restrict__ wc2,           // [8][512][4][8] bf16 image
    const float* __restrict__ b_clip1, const float* __restrict__ bn_clip,
    const float* __restrict__ b_clip2,
    float* __restrict__ out_lab, float* __restrict__ out_unlab, float* __restrict__ out_over,
    float* __restrict__ outc)
{
    extern __shared__ __align__(16) char lds[];
    char* reg0 = lds;            // 65536
    char* s_h  = lds + 65536;    // 65536

    const int t   = threadIdx.x;
    const int wid = t >> 6;
    const int l   = t & 63;
    const int l15 = l & 15;
    const int l4  = l >> 4;
    const int wm  = wid >> 2;
    const int wn  = wid & 3;
    const int r0  = blockIdx.x * 128;

#define STG1(kt) do {                                                          \
    const char* _s = wc1h + (size_t)(kt) * 24576;                              \
    char* _d = reg0 + ((kt) & 1) * 32768;                                      \
    _Pragma("unroll")                                                          \
    for (int _i = 0; _i < 3; ++_i)                                             \
        gload16(_s + _i * 8192 + t * 16, _d + _i * 8192 + (wid << 10));        \
} while (0)

#define STG2(kt) do {                                                          \
    const char* _s = wc2 + (size_t)(kt) * 32768;                               \
    char* _d = reg0 + ((kt) & 1) * 32768;                                      \
    _Pragma("unroll")                                                          \
    for (int _i = 0; _i < 4; ++_i)                                             \
        gload16(_s + _i * 8192 + t * 16, _d + _i * 8192 + (wid << 10));        \
} while (0)

    // ================= phase 1 =================
    STG1(0);

    s16x8 af[3][4];
    #pragma unroll
    for (int kt = 0; kt < 3; ++kt)
        #pragma unroll
        for (int mt = 0; mt < 4; ++mt) {
            const int r = r0 + wm*64 + mt*16 + l15;
            const float* bp = x + (size_t)r*96 + kt*32 + l4*8;
            const float4 xa = *(const float4*)bp;
            const float4 xb = *(const float4*)(bp + 4);
            s16x8 v;
            v[0]=(short)f2bf(xa.x); v[1]=(short)f2bf(xa.y); v[2]=(short)f2bf(xa.z); v[3]=(short)f2bf(xa.w);
            v[4]=(short)f2bf(xb.x); v[5]=(short)f2bf(xb.y); v[6]=(short)f2bf(xb.z); v[7]=(short)f2bf(xb.w);
            af[kt][mt] = v;
        }

    f32x4 acc1[4][6];
    #pragma unroll
    for (int mt = 0; mt < 4; ++mt)
        #pragma unroll
        for (int nt = 0; nt < 6; ++nt) acc1[mt][nt] = (f32x4){0.f,0.f,0.f,0.f};

    __syncthreads();

    for (int kt = 0; kt < 3; ++kt) {
        if (kt < 2) STG1(kt + 1);
        const char* buf = reg0 + (kt & 1) * 32768;
        s16x8 bf[6];
        #pragma unroll
        for (int nt = 0; nt < 6; ++nt) {
            const int col = wn*96 + nt*16 + l15;
            bf[nt] = *(const s16x8*)(buf + col*64 + ((l4 ^ ((col >> 2) & 3)) << 4));
        }
        #pragma unroll
        for (int nt = 0; nt < 6; ++nt)
            #pragma unroll
            for (int mt = 0; mt < 4; ++mt)
                acc1[mt][nt] = __builtin_amdgcn_mfma_f32_16x16x32_bf16(af[kt][mt], bf[nt], acc1[mt][nt], 0, 0, 0);
        __syncthreads();
    }

    STG2(0);

    #pragma unroll
    for (int nt = 0; nt < 6; ++nt) {
        const int j = wn*96 + nt*16 + l15;
        if (j < 256) {
            const float sc = bn_clip[j] * rsqrtf(bn_clip[768 + j] + EPS_BN);
            const float mb = bn_clip[512 + j];
            const float bb = bn_clip[256 + j];
            const float bias = b_clip1[j];
            const int c = j >> 3, e = j & 7;
            #pragma unroll
            for (int mt = 0; mt < 4; ++mt)
                #pragma unroll
                for (int q = 0; q < 4; ++q) {
                    const int row = wm*64 + mt*16 + l4*4 + q;
                    float y = fmaxf(sc * (acc1[mt][nt][q] + bias - mb) + bb, 0.f);
                    *(unsigned short*)(s_h + row*512 + ((c ^ (row & 31)) << 4) + e*2) = f2bf(y);
                }
        } else if (j < 375) {
            const int jh = j - 256;
            #pragma unroll
            for (int mt = 0; mt < 4; ++mt)
                #pragma unroll
                for (int q = 0; q < 4; ++q) {
                    const int n = r0 + wm*64 + mt*16 + l4*4 + q;
                    const float v = acc1[mt][nt][q];
                    if (jh < 19)      out_lab[(size_t)n*19 + jh] = v;
                    else if (jh < 44) { int jj = jh-19, hh = jj/5,  p = jj-hh*5;  out_unlab[((size_t)hh*NNODES + n)*5  + p] = v; }
                    else              { int jj = jh-44, hh = jj/15, p = jj-hh*15; out_over [((size_t)hh*NNODES + n)*15 + p] = v; }
                }
        }
    }
    __syncthreads();

    // ================= phase 2: h @ w_clip2 =================
    f32x4 acc2[4][8];
    #pragma unroll
    for (int mt = 0; mt < 4; ++mt)
        #pragma unroll
        for (int nt = 0; nt < 8; ++nt) acc2[mt][nt] = (f32x4){0.f,0.f,0.f,0.f};

    for (int kt = 0; kt < 8; ++kt) {
        if (kt < 7) STG2(kt + 1);
        const char* buf = reg0 + (kt & 1) * 32768;
        s16x8 a2[4];
        #pragma unroll
        for (int mt = 0; mt < 4; ++mt) {
            const int row = wm*64 + mt*16 + l15;
            a2[mt] = *(const s16x8*)(s_h + row*512 + (((kt*4 + l4) ^ (row & 31)) << 4));
        }
        s16x8 b2[8];
        #pragma unroll
        for (int nt = 0; nt < 8; ++nt) {
            const int col = wn*128 + nt*16 + l15;
            b2[nt] = *(const s16x8*)(buf + col*64 + ((l4 ^ ((col >> 2) & 3)) << 4));
        }
        #pragma unroll
        for (int nt = 0; nt < 8; ++nt)
            #pragma unroll
            for (int mt = 0; mt < 4; ++mt)
                acc2[mt][nt] = __builtin_amdgcn_mfma_f32_16x16x32_bf16(a2[mt], b2[nt], acc2[mt][nt], 0, 0, 0);
        __syncthreads();
    }
#undef STG1
#undef STG2

    #pragma unroll
    for (int nt = 0; nt < 8; ++nt) {
        const int col = wn*128 + nt*16 + l15;
        const float bb = b_clip2[col];
        #pragma unroll
        for (int mt = 0; mt < 4; ++mt)
            #pragma unroll
            for (int q = 0; q < 4; ++q) {
                const int row = wm*64 + mt*16 + l4*4 + q;
                outc[(size_t)(r0 + row)*512 + col] = acc2[mt][nt][q] + bb;
            }
    }
}

extern "C" void kernel_launch(void* const* d_in, const int* in_sizes, int n_in,
                              void* d_out, int out_size, void* d_ws, size_t ws_size,
                              hipStream_t stream)
{
    const float* feats   = (const float*)d_in[0];
    const int*   nbr1    = (const int*)  d_in[1];
    const int*   nbr2    = (const int*)  d_in[2];
    const float* w_rgb   = (const float*)d_in[3];
    const float* b_rgb   = (const float*)d_in[4];
    const float* bn_rgb  = (const float*)d_in[5];
    const float* w_img   = (const float*)d_in[6];
    const float* b_img   = (const float*)d_in[7];
    const float* bn_img  = (const float*)d_in[8];
    const float* w_e1    = (const float*)d_in[9];
    const float* w_e2    = (const float*)d_in[10];
    const float* bn_e1   = (const float*)d_in[11];
    const float* bn_e2   = (const float*)d_in[12];
    const float* w_lab   = (const float*)d_in[13];
    const float* w_unlab = (const float*)d_in[14];
    const float* w_over  = (const float*)d_in[15];
    const float* w_clip1 = (const float*)d_in[16];
    const float* b_clip1 = (const float*)d_in[17];
    const float* bn_clip = (const float*)d_in[18];
    const float* w_clip2 = (const float*)d_in[19];
    const float* b_clip2 = (const float*)d_in[20];

    float* out = (float*)d_out;
    const size_t off_unlab = (size_t)NNODES * 19;
    const size_t off_over  = (size_t)NNODES * 44;
    const size_t off_x     = (size_t)NNODES * 119;
    const size_t off_clip  = (size_t)NNODES * 215;

    // intermediates inside clip-feats output region — only read by kernels that
    // run BEFORE fused_clip_heads (the sole writer of this region)
    char* scratch = (char*)(out + off_clip);
    unsigned short* x64b  = (unsigned short*)scratch;                   // 8 MB
    unsigned short* x96b  = (unsigned short*)(scratch + (8u << 20));    // 12.6 MB
    unsigned short* wpre1 = (unsigned short*)(scratch + (21u << 20));   // 332 KB
    unsigned short* wpre2 = (unsigned short*)(scratch + (22u << 20));   // 664 KB

    // weight images read BY fused_clip_heads live in d_ws (336 KB)
    char* wc1h = (char*)d_ws;               // 73728 B
    char* wc2  = (char*)d_ws + 73728;       // 262144 B

    prep_w_kernel<<<(KNBR*96*8*8  + 255) / 256, 256, 0, stream>>>(w_e1, wpre1, 64, 8);
    prep_w_kernel<<<(KNBR*96*16*8 + 255) / 256, 256, 0, stream>>>(w_e2, wpre2, 96, 16);
    prep_wc1h_kernel<<<(3*384*32 + 255) / 256, 256, 0, stream>>>(w_clip1, w_lab, w_unlab, w_over,
                                                                 (unsigned short*)wc1h);
    prep_wc2_kernel<<<131072 / 256, 256, 0, stream>>>(w_clip2, (unsigned short*)wc2);

    stage1_kernel<<<NNODES/4, 256, 0, stream>>>(feats, w_rgb, b_rgb, bn_rgb, w_img, b_img, bn_img, x64b);

    spconv_mfma<64, true ><<<NNODES/128, 256, 0, stream>>>((const char*)x64b, nbr1, (const char*)wpre1,
                                                           bn_e1, nullptr, x96b);
    spconv_mfma<96, false><<<NNODES/128, 256, 0, stream>>>((const char*)x96b, nbr2, (const char*)wpre2,
                                                           bn_e2, out + off_x, nullptr);

    fused_clip_heads<<<NNODES/128, 512, 131072, stream>>>(
        out + off_x, wc1h, wc2, b_clip1, bn_clip, b_clip2,
        out, out + off_unlab, out + off_over, out + off_clip);
}

// Round 9
// 234.474 us; speedup vs baseline: 1.3764x; 1.0297x over previous
//
#include <hip/hip_runtime.h>
#include <math.h>

#define NNODES 65536
#define KNBR 27
#define EPS_BN 1e-5f
#define LOG_P 4.6151205168412597f

typedef float f32x4 __attribute__((ext_vector_type(4)));
typedef short s16x8 __attribute__((ext_vector_type(8)));   // 8 bf16 in 4 VGPRs

__device__ __forceinline__ unsigned short f2bf(float f) {
    union { float f; unsigned int u; } v; v.f = f;
    unsigned int u = v.u;
    unsigned int r = (u + 0x7fffu + ((u >> 16) & 1u)) >> 16;   // RNE
    return (unsigned short)r;
}

__device__ __forceinline__ void gload16(const void* g, void* l) {
    __builtin_amdgcn_global_load_lds(
        (const __attribute__((address_space(1))) void*)g,
        (__attribute__((address_space(3))) void*)l, 16, 0, 0);
}

// ---------------- one prep kernel for all 4 weight images ----------------
// region 1: wpre1 [27][96][8 ci][8 e]  (CIN=64,  NCH=8)
// region 2: wpre2 [27][96][16 ci][8 e] (CIN=96,  NCH=16)
// region 3: wc1h  [3 kt][384 col][4 p][8 e]
// region 4: wc2   [8 kt][512 col][4 p][8 e]
__global__ __launch_bounds__(256) void prep_all_kernel(
    const float* __restrict__ w_e1, const float* __restrict__ w_e2,
    const float* __restrict__ w_clip1, const float* __restrict__ w_lab,
    const float* __restrict__ w_unlab, const float* __restrict__ w_over,
    const float* __restrict__ w_clip2,
    unsigned short* __restrict__ wpre1, unsigned short* __restrict__ wpre2,
    unsigned short* __restrict__ wc1h, unsigned short* __restrict__ wc2)
{
    const int N1 = KNBR*96*8*8;          // 165888
    const int N2 = KNBR*96*16*8;         // 331776
    const int N3 = 3*384*32;             // 36864
    const int N4 = 8*512*32;             // 131072
    int idx = blockIdx.x * 256 + threadIdx.x;
    if (idx < N1) {
        const int e = idx & 7, ci = (idx >> 3) & 7, r = (idx >> 6) % 96, k = (idx >> 6) / 96;
        const int cin = (ci ^ (r & 7)) * 8 + e;
        wpre1[idx] = f2bf(w_e1[((size_t)k*64 + cin)*96 + r]);
        return;
    }
    idx -= N1;
    if (idx < N2) {
        const int e = idx & 7, ci = (idx >> 3) & 15, r = (idx >> 7) % 96, k = (idx >> 7) / 96;
        const int cin = (ci ^ (r & 15)) * 8 + e;
        wpre2[idx] = f2bf(w_e2[((size_t)k*96 + cin)*96 + r]);
        return;
    }
    idx -= N2;
    if (idx < N3) {
        const int e = idx & 7, p2 = (idx >> 3) & 3, col = (idx >> 5) % 384, kt = (idx >> 5) / 384;
        const int cin = (kt*4 + (p2 ^ ((col >> 2) & 3)))*8 + e;
        float v;
        if (col < 256)      v = w_clip1[(size_t)cin*256 + col];
        else if (col < 275) v = w_lab[(size_t)cin*19 + (col - 256)];
        else if (col < 300) { int jj = col-275, hh = jj/5,  p = jj-hh*5;  v = w_unlab[((size_t)hh*96 + cin)*5  + p]; }
        else if (col < 375) { int jj = col-300, hh = jj/15, p = jj-hh*15; v = w_over [((size_t)hh*96 + cin)*15 + p]; }
        else v = 0.f;
        wc1h[idx] = f2bf(v);
        return;
    }
    idx -= N3;
    if (idx < N4) {
        const int e = idx & 7, p2 = (idx >> 3) & 3, col = (idx >> 5) & 511, kt = idx >> 14;
        const int cin = (kt*4 + (p2 ^ ((col >> 2) & 3)))*8 + e;
        wc2[idx] = f2bf(w_clip2[(size_t)cin*512 + col]);
    }
}

// ---------------- stage 1: entropy gate + rgb/img matvec -> x64 (bf16) ----------------
__global__ __launch_bounds__(256) void stage1_kernel(
    const float* __restrict__ feats,
    const float* __restrict__ w_rgb, const float* __restrict__ b_rgb, const float* __restrict__ bn_rgb,
    const float* __restrict__ w_img, const float* __restrict__ b_img, const float* __restrict__ bn_img,
    unsigned short* __restrict__ x64b)
{
    __shared__ float s_f[4][106];
    const int wid  = threadIdx.x >> 6;
    const int lane = threadIdx.x & 63;
    const int n = blockIdx.x * 4 + wid;
    const float* fr = feats + (size_t)n * 105;
    for (int i = lane; i < 105; i += 64) s_f[wid][i] = fr[i];
    __syncthreads();

    float s = 0.f;
    for (int i = lane; i < 101; i += 64) {
        float pv = s_f[wid][4 + i];
        float ps = fmaxf(pv, 1e-12f);
        s += ps * logf(ps);
    }
    #pragma unroll
    for (int off = 32; off > 0; off >>= 1) s += __shfl_xor(s, off, 64);
    const float wgt = 1.0f + s * (1.0f / LOG_P);

    if (lane < 32) {
        const int j = lane;
        float acc = b_rgb[j];
        #pragma unroll
        for (int c = 0; c < 4; ++c) acc += s_f[wid][c] * w_rgb[c*32 + j];
        float y = bn_rgb[j] * (acc - bn_rgb[64+j]) * rsqrtf(bn_rgb[96+j] + EPS_BN) + bn_rgb[32+j];
        x64b[(size_t)n*64 + j] = f2bf(fmaxf(y, 0.f));
    } else {
        const int j = lane - 32;
        float acc = 0.f;
        for (int c = 0; c < 101; ++c) acc += s_f[wid][4+c] * w_img[c*32 + j];
        acc = acc * wgt + b_img[j];
        float y = bn_img[j] * (acc - bn_img[64+j]) * rsqrtf(bn_img[96+j] + EPS_BN) + bn_img[32+j];
        x64b[(size_t)n*64 + 32 + j] = f2bf(fmaxf(y, 0.f));
    }
}

// ---------------- spconv via MFMA (r8, proven): r4 geometry + T4 counted-vmcnt ----------------
template<int CIN, bool OUTBF>
__global__ __launch_bounds__(256, 2) void spconv_mfma(
    const char* __restrict__ xinb,
    const int*  __restrict__ nbr,
    const char* __restrict__ wpre,
    const float* __restrict__ bnp,
    float* __restrict__ outf,
    unsigned short* __restrict__ outb)
{
    constexpr int KT   = CIN / 32;
    constexpr int NCH  = (CIN == 96) ? 16 : 8;
    constexpr int CM   = NCH - 1;
    constexpr int ROWB = NCH * 16;
    constexpr int STG  = (96 * ROWB) / 4096;

    __shared__ int s_nbr[128 * KNBR];
    __shared__ __align__(16) char s_b[2][96 * ROWB];

    const int t   = threadIdx.x;
    const int wid = t >> 6;
    const int l   = t & 63;
    const int l15 = l & 15;
    const int l4  = l >> 4;
    const int n0  = blockIdx.x * 128;

    for (int i = t; i < 128 * KNBR; i += 256) s_nbr[i] = nbr[(size_t)n0 * KNBR + i];

    f32x4 acc[2][6];
    #pragma unroll
    for (int mt = 0; mt < 2; ++mt)
        #pragma unroll
        for (int nt = 0; nt < 6; ++nt) acc[mt][nt] = (f32x4){0.f, 0.f, 0.f, 0.f};

    s16x8 a0[2][KT], a1[2][KT], a2r[2][KT];

#define STAGE(kk) do {                                                         \
    const char* _src = wpre + (size_t)(kk) * (96 * ROWB);                      \
    char* _dst = &s_b[(kk) & 1][0];                                            \
    _Pragma("unroll")                                                          \
    for (int _i = 0; _i < STG; ++_i)                                           \
        gload16(_src + _i * 4096 + t * 16, _dst + _i * 4096 + (wid << 10));    \
    asm volatile("" ::: "memory");                                             \
} while (0)

#define PRE(areg, kk) do {                                                     \
    _Pragma("unroll")                                                          \
    for (int _mt = 0; _mt < 2; ++_mt) {                                        \
        const int _nb = s_nbr[(wid * 32 + _mt * 16 + l15) * KNBR + (kk)];      \
        const char* _rp = xinb + (size_t)_nb * (CIN * 2) + (l4 << 4);          \
        _Pragma("unroll")                                                      \
        for (int _kt = 0; _kt < KT; ++_kt)                                     \
            areg[_mt][_kt] = *(const s16x8*)(_rp + _kt * 64);                  \
    }                                                                          \
} while (0)

#define COMP(areg, kk) do {                                                    \
    const char* _bb = &s_b[(kk) & 1][0];                                       \
    _Pragma("unroll")                                                          \
    for (int _kt = 0; _kt < KT; ++_kt) {                                       \
        s16x8 _bf[6];                                                          \
        _Pragma("unroll")                                                      \
        for (int _nt = 0; _nt < 6; ++_nt) {                                    \
            const int _row = _nt * 16 + l15;                                   \
            const int _c   = _kt * 4 + l4;                                     \
            _bf[_nt] = *(const s16x8*)(_bb + _row * ROWB + ((_c ^ (_row & CM)) << 4)); \
        }                                                                      \
        _Pragma("unroll")                                                      \
        for (int _nt = 0; _nt < 6; ++_nt) {                                    \
            acc[0][_nt] = __builtin_amdgcn_mfma_f32_16x16x32_bf16(areg[0][_kt], _bf[_nt], acc[0][_nt], 0, 0, 0); \
            acc[1][_nt] = __builtin_amdgcn_mfma_f32_16x16x32_bf16(areg[1][_kt], _bf[_nt], acc[1][_nt], 0, 0, 0); \
        }                                                                      \
    }                                                                          \
} while (0)

#define KBAR() do {                                                            \
    if (KT == 3) asm volatile("s_waitcnt vmcnt(6)" ::: "memory");              \
    else         asm volatile("s_waitcnt vmcnt(4)" ::: "memory");              \
    __builtin_amdgcn_s_barrier();                                              \
} while (0)

    __syncthreads();                 // s_nbr ready
    PRE(a0, 0);
    PRE(a1, 1);
    STAGE(0);
    __syncthreads();                 // prologue full drain (once)

    for (int k = 0; k < 24; k += 3) {
        STAGE(k + 1);
        PRE(a2r, k + 2);
        COMP(a0, k);
        KBAR();
        STAGE(k + 2);
        PRE(a0, k + 3);
        COMP(a1, k + 1);
        KBAR();
        STAGE(k + 3);
        PRE(a1, k + 4);
        COMP(a2r, k + 2);
        KBAR();
    }
    STAGE(25);
    PRE(a2r, 26);
    COMP(a0, 24);
    KBAR();
    STAGE(26);
    COMP(a1, 25);
    asm volatile("s_waitcnt vmcnt(0)" ::: "memory");
    __builtin_amdgcn_s_barrier();
    COMP(a2r, 26);

#undef STAGE
#undef PRE
#undef COMP
#undef KBAR

    #pragma unroll
    for (int mt = 0; mt < 2; ++mt)
        #pragma unroll
        for (int nt = 0; nt < 6; ++nt) {
            const int d = nt * 16 + l15;
            const float sc = bnp[d] * rsqrtf(bnp[288 + d] + EPS_BN);
            const float mb = bnp[192 + d];
            const float bb = bnp[96 + d];
            #pragma unroll
            for (int q = 0; q < 4; ++q) {
                const int node = n0 + wid * 32 + mt * 16 + l4 * 4 + q;
                float y = sc * (acc[mt][nt][q] - mb) + bb;
                y = fmaxf(y, 0.f);
                if (OUTBF) outb[(size_t)node * 96 + d] = f2bf(y);
                else       outf[(size_t)node * 96 + d] = y;
            }
        }
}

// ---------------- fused clip1 + heads + clip2: 64 rows/block, 64 KiB LDS, 2 blocks/CU ----------------
// LDS: reg0 [0,32K): single-buffered B stage (phase1 24.5K / phase2 32K)
//      s_h  [32K,64K): h [64 rows][32 chunk-pos][8 e] bf16, pos = c ^ (row&31)
__global__ __launch_bounds__(512, 4) void fused_clip_heads(
    const float* __restrict__ x,
    const char* __restrict__ wc1h,          // [3][384][4][8] bf16 image
    const char* __restrict__ wc2,           // [8][512][4][8] bf16 image
    const float* __restrict__ b_clip1, const float* __restrict__ bn_clip,
    const float* __restrict__ b_clip2,
    float* __restrict__ out_lab, float* __restrict__ out_unlab, float* __restrict__ out_over,
    float* __restrict__ outc)
{
    extern __shared__ __align__(16) char lds[];
    char* reg0 = lds;            // 32768
    char* s_h  = lds + 32768;    // 32768

    const int t   = threadIdx.x;
    const int wid = t >> 6;
    const int l   = t & 63;
    const int l15 = l & 15;
    const int l4  = l >> 4;
    const int wm  = wid >> 2;    // 0..1 (row half: 32 rows)
    const int wn  = wid & 3;     // 0..3 (col group)
    const int r0  = blockIdx.x * 64;

#define STG1(kt) do {                                                          \
    const char* _s = wc1h + (size_t)(kt) * 24576;                              \
    _Pragma("unroll")                                                          \
    for (int _i = 0; _i < 3; ++_i)                                             \
        gload16(_s + _i * 8192 + t * 16, reg0 + _i * 8192 + (wid << 10));      \
} while (0)

#define STG2(kt) do {                                                          \
    const char* _s = wc2 + (size_t)(kt) * 32768;                               \
    _Pragma("unroll")                                                          \
    for (int _i = 0; _i < 4; ++_i)                                             \
        gload16(_s + _i * 8192 + t * 16, reg0 + _i * 8192 + (wid << 10));      \
} while (0)

    // ================= phase 1: x @ [w_clip1 | heads] =================
    // A frags: 64 rows, mt=0..1, kt=0..2 (f32 -> bf16 on the fly)
    s16x8 af[3][2];
    #pragma unroll
    for (int kt = 0; kt < 3; ++kt)
        #pragma unroll
        for (int mt = 0; mt < 2; ++mt) {
            const int r = r0 + wm*32 + mt*16 + l15;
            const float* bp = x + (size_t)r*96 + kt*32 + l4*8;
            const float4 xa = *(const float4*)bp;
            const float4 xb = *(const float4*)(bp + 4);
            s16x8 v;
            v[0]=(short)f2bf(xa.x); v[1]=(short)f2bf(xa.y); v[2]=(short)f2bf(xa.z); v[3]=(short)f2bf(xa.w);
            v[4]=(short)f2bf(xb.x); v[5]=(short)f2bf(xb.y); v[6]=(short)f2bf(xb.z); v[7]=(short)f2bf(xb.w);
            af[kt][mt] = v;
        }

    f32x4 acc1[2][6];
    #pragma unroll
    for (int mt = 0; mt < 2; ++mt)
        #pragma unroll
        for (int nt = 0; nt < 6; ++nt) acc1[mt][nt] = (f32x4){0.f,0.f,0.f,0.f};

    for (int kt = 0; kt < 3; ++kt) {
        STG1(kt);                       // reg0 free: first iter fresh, later iters protected by loop-tail sync
        __syncthreads();                // staging complete
        s16x8 bf[6];
        #pragma unroll
        for (int nt = 0; nt < 6; ++nt) {
            const int col = wn*96 + nt*16 + l15;
            bf[nt] = *(const s16x8*)(reg0 + col*64 + ((l4 ^ ((col >> 2) & 3)) << 4));
        }
        #pragma unroll
        for (int nt = 0; nt < 6; ++nt)
            #pragma unroll
            for (int mt = 0; mt < 2; ++mt)
                acc1[mt][nt] = __builtin_amdgcn_mfma_f32_16x16x32_bf16(af[kt][mt], bf[nt], acc1[mt][nt], 0, 0, 0);
        __syncthreads();                // reads done -> next stage may overwrite
    }

    STG2(0);   // prefetch first w2 tile under epilogue 1 (reg0 reads finished above)

    // epilogue 1: h -> s_h (swizzled bf16); heads -> global scatter
    #pragma unroll
    for (int nt = 0; nt < 6; ++nt) {
        const int j = wn*96 + nt*16 + l15;
        if (j < 256) {
            const float sc = bn_clip[j] * rsqrtf(bn_clip[768 + j] + EPS_BN);
            const float mb = bn_clip[512 + j];
            const float bb = bn_clip[256 + j];
            const float bias = b_clip1[j];
            const int c = j >> 3, e = j & 7;
            #pragma unroll
            for (int mt = 0; mt < 2; ++mt)
                #pragma unroll
                for (int q = 0; q < 4; ++q) {
                    const int row = wm*32 + mt*16 + l4*4 + q;
                    float y = fmaxf(sc * (acc1[mt][nt][q] + bias - mb) + bb, 0.f);
                    *(unsigned short*)(s_h + row*512 + ((c ^ (row & 31)) << 4) + e*2) = f2bf(y);
                }
        } else if (j < 375) {
            const int jh = j - 256;
            #pragma unroll
            for (int mt = 0; mt < 2; ++mt)
                #pragma unroll
                for (int q = 0; q < 4; ++q) {
                    const int n = r0 + wm*32 + mt*16 + l4*4 + q;
                    const float v = acc1[mt][nt][q];
                    if (jh < 19)      out_lab[(size_t)n*19 + jh] = v;
                    else if (jh < 44) { int jj = jh-19, hh = jj/5,  p = jj-hh*5;  out_unlab[((size_t)hh*NNODES + n)*5  + p] = v; }
                    else              { int jj = jh-44, hh = jj/15, p = jj-hh*15; out_over [((size_t)hh*NNODES + n)*15 + p] = v; }
                }
        }
    }
    __syncthreads();   // s_h complete + STG2(0) landed

    // ================= phase 2: h @ w_clip2 =================
    f32x4 acc2[2][8];
    #pragma unroll
    for (int mt = 0; mt < 2; ++mt)
        #pragma unroll
        for (int nt = 0; nt < 8; ++nt) acc2[mt][nt] = (f32x4){0.f,0.f,0.f,0.f};

    for (int kt = 0; kt < 8; ++kt) {
        s16x8 a2[2];
        #pragma unroll
        for (int mt = 0; mt < 2; ++mt) {
            const int row = wm*32 + mt*16 + l15;
            a2[mt] = *(const s16x8*)(s_h + row*512 + (((kt*4 + l4) ^ (row & 31)) << 4));
        }
        s16x8 b2[8];
        #pragma unroll
        for (int nt = 0; nt < 8; ++nt) {
            const int col = wn*128 + nt*16 + l15;
            b2[nt] = *(const s16x8*)(reg0 + col*64 + ((l4 ^ ((col >> 2) & 3)) << 4));
        }
        #pragma unroll
        for (int nt = 0; nt < 8; ++nt)
            #pragma unroll
            for (int mt = 0; mt < 2; ++mt)
                acc2[mt][nt] = __builtin_amdgcn_mfma_f32_16x16x32_bf16(a2[mt], b2[nt], acc2[mt][nt], 0, 0, 0);
        __syncthreads();                // reg0 reads done
        if (kt < 7) {
            STG2(kt + 1);               // overwrite reg0
            __syncthreads();            // staging complete before next reads
        }
    }
#undef STG1
#undef STG2

    // epilogue 2: + bias, f32 out
    #pragma unroll
    for (int nt = 0; nt < 8; ++nt) {
        const int col = wn*128 + nt*16 + l15;
        const float bb = b_clip2[col];
        #pragma unroll
        for (int mt = 0; mt < 2; ++mt)
            #pragma unroll
            for (int q = 0; q < 4; ++q) {
                const int row = wm*32 + mt*16 + l4*4 + q;
                outc[(size_t)(r0 + row)*512 + col] = acc2[mt][nt][q] + bb;
            }
    }
}

extern "C" void kernel_launch(void* const* d_in, const int* in_sizes, int n_in,
                              void* d_out, int out_size, void* d_ws, size_t ws_size,
                              hipStream_t stream)
{
    const float* feats   = (const float*)d_in[0];
    const int*   nbr1    = (const int*)  d_in[1];
    const int*   nbr2    = (const int*)  d_in[2];
    const float* w_rgb   = (const float*)d_in[3];
    const float* b_rgb   = (const float*)d_in[4];
    const float* bn_rgb  = (const float*)d_in[5];
    const float* w_img   = (const float*)d_in[6];
    const float* b_img   = (const float*)d_in[7];
    const float* bn_img  = (const float*)d_in[8];
    const float* w_e1    = (const float*)d_in[9];
    const float* w_e2    = (const float*)d_in[10];
    const float* bn_e1   = (const float*)d_in[11];
    const float* bn_e2   = (const float*)d_in[12];
    const float* w_lab   = (const float*)d_in[13];
    const float* w_unlab = (const float*)d_in[14];
    const float* w_over  = (const float*)d_in[15];
    const float* w_clip1 = (const float*)d_in[16];
    const float* b_clip1 = (const float*)d_in[17];
    const float* bn_clip = (const float*)d_in[18];
    const float* w_clip2 = (const float*)d_in[19];
    const float* b_clip2 = (const float*)d_in[20];

    float* out = (float*)d_out;
    const size_t off_unlab = (size_t)NNODES * 19;
    const size_t off_over  = (size_t)NNODES * 44;
    const size_t off_x     = (size_t)NNODES * 119;
    const size_t off_clip  = (size_t)NNODES * 215;

    // intermediates inside clip-feats output region — only read by kernels that
    // run BEFORE fused_clip_heads (the sole writer of this region)
    char* scratch = (char*)(out + off_clip);
    unsigned short* x64b  = (unsigned short*)scratch;                   // 8 MB
    unsigned short* x96b  = (unsigned short*)(scratch + (8u << 20));    // 12.6 MB
    unsigned short* wpre1 = (unsigned short*)(scratch + (21u << 20));   // 332 KB
    unsigned short* wpre2 = (unsigned short*)(scratch + (22u << 20));   // 664 KB

    // weight images read BY fused_clip_heads live in d_ws (336 KB)
    char* wc1h = (char*)d_ws;               // 73728 B
    char* wc2  = (char*)d_ws + 73728;       // 262144 B

    const int NPREP = KNBR*96*8*8 + KNBR*96*16*8 + 3*384*32 + 8*512*32;   // 665600
    prep_all_kernel<<<(NPREP + 255) / 256, 256, 0, stream>>>(
        w_e1, w_e2, w_clip1, w_lab, w_unlab, w_over, w_clip2,
        wpre1, wpre2, (unsigned short*)wc1h, (unsigned short*)wc2);

    stage1_kernel<<<NNODES/4, 256, 0, stream>>>(feats, w_rgb, b_rgb, bn_rgb, w_img, b_img, bn_img, x64b);

    spconv_mfma<64, true ><<<NNODES/128, 256, 0, stream>>>((const char*)x64b, nbr1, (const char*)wpre1,
                                                           bn_e1, nullptr, x96b);
    spconv_mfma<96, false><<<NNODES/128, 256, 0, stream>>>((const char*)x96b, nbr2, (const char*)wpre2,
                                                           bn_e2, out + off_x, nullptr);

    fused_clip_heads<<<NNODES/64, 512, 65536, stream>>>(
        out + off_x, wc1h, wc2, b_clip1, bn_clip, b_clip2,
        out, out + off_unlab, out + off_over, out + off_clip);
}